// Round 3
// baseline (798.695 us; speedup 1.0000x reference)
//
#include <hip/hip_runtime.h>
#include <cstdint>

#define B_ 16
#define H_ 224
#define W_ 224
#define C_ 32
#define TS 32      // output tile 32x32, 224 = 7*32
#define RG 47      // data rows/cols in halo region (32 + 7 top + 8 bottom)
#define SR 48      // SAT dim: exclusive 2D prefix needs +1 row & col

// ---- order-preserving float<->uint encoding for atomic min/max ----
__device__ __forceinline__ unsigned int enc_f(float f) {
    unsigned int u = __float_as_uint(f);
    return (u & 0x80000000u) ? ~u : (u | 0x80000000u);
}
__device__ __forceinline__ float dec_f(unsigned int u) {
    u = (u & 0x80000000u) ? (u & 0x7FFFFFFFu) : ~u;
    return __uint_as_float(u);
}

__global__ void init_ws(unsigned int* __restrict__ ws) {
    int t = threadIdx.x;
    if (t < 16) ws[t] = 0xFFFFFFFFu;
    else if (t < 32) ws[t] = 0u;
}

__global__ __launch_bounds__(256) void minmax_kernel(const float* __restrict__ x,
                                                     unsigned int* __restrict__ ws) {
    const int b = blockIdx.x;
    const int chunk = blockIdx.y;
    const int chunkElems = (H_ * W_ * C_) / 64;
    const float4* p = (const float4*)(x + (size_t)b * (H_ * W_ * C_) +
                                      (size_t)chunk * chunkElems);
    const int n4 = chunkElems / 4;
    float mn = 3.4e38f, mx = -3.4e38f;
    for (int i = threadIdx.x; i < n4; i += 256) {
        float4 v = p[i];
        mn = fminf(mn, fminf(fminf(v.x, v.y), fminf(v.z, v.w)));
        mx = fmaxf(mx, fmaxf(fmaxf(v.x, v.y), fmaxf(v.z, v.w)));
    }
#pragma unroll
    for (int off = 32; off > 0; off >>= 1) {
        mn = fminf(mn, __shfl_down(mn, off));
        mx = fmaxf(mx, __shfl_down(mx, off));
    }
    __shared__ float smn[4], smx[4];
    const int lane = threadIdx.x & 63, wv = threadIdx.x >> 6;
    if (lane == 0) { smn[wv] = mn; smx[wv] = mx; }
    __syncthreads();
    if (threadIdx.x == 0) {
        mn = fminf(fminf(smn[0], smn[1]), fminf(smn[2], smn[3]));
        mx = fmaxf(fmaxf(smx[0], smx[1]), fmaxf(smx[2], smx[3]));
        atomicMin(&ws[b], enc_f(mn));
        atomicMax(&ws[16 + b], enc_f(mx));
    }
}

// Box sum via 2D exclusive SAT corner reads, 4 channels (one float4) per phase.
// Round-3 change: each block reads its FULL 64B half-line once (cc=0) and
// stashes the other 3 channel-quads in registers; outputs are accumulated in
// registers and written as one contiguous 64B burst at the end. This removes
// the 16B/sector read amplification (506MB fetch) and the partial-sector
// write amplification (243MB write) seen in round 2.
#define LG(v) __log2f(fmaxf((v), 0.0f) + 1e-7f)

#define BOX(o, sc, bx) {                                                 \
        float4 q00 = SAT[hl + (o)][wl + (o)];                            \
        float4 q01 = SAT[hl + (o)][wl + (o) + (sc)];                     \
        float4 q10 = SAT[hl + (o) + (sc)][wl + (o)];                     \
        float4 q11 = SAT[hl + (o) + (sc)][wl + (o) + (sc)];              \
        bx.x = q11.x - q01.x - q10.x + q00.x;                            \
        bx.y = q11.y - q01.y - q10.y + q00.y;                            \
        bx.z = q11.z - q01.z - q10.z + q00.z;                            \
        bx.w = q11.w - q01.w - q10.w + q00.w; }

#define SC4(q) { q.x = (q.x - mn) * inv; q.y = (q.y - mn) * inv;         \
                 q.z = (q.z - mn) * inv; q.w = (q.w - mn) * inv; }

__global__ __launch_bounds__(512, 4) void lss_kernel(
    const float* __restrict__ x,
    const float* __restrict__ gamma, const float* __restrict__ beta,
    const float* __restrict__ mmean, const float* __restrict__ mvar,
    const unsigned int* __restrict__ ws,
    float* __restrict__ out)
{
    __shared__ float4 SAT[SR][SR];   // 36,864 B -> 2 blocks/CU at <=128 VGPR

    const int bi = blockIdx.x;
    const int grp = bi >> 4, wi = bi & 15;
    const int s = (wi >> 3) & 1;           // channel half: ch s*16 .. s*16+15
    const int tile = grp * 8 + (wi & 7);   // splits of a tile land on same XCD
    const int b = tile / 49;
    const int t2 = tile - b * 49;
    const int th0 = (t2 / 7) * TS;
    const int tw0 = (t2 % 7) * TS;
    const int tid = threadIdx.x;
    const int lane = tid & 63, wv = tid >> 6;   // 8 waves

    const float mn = dec_f(ws[b]);
    const float mx = dec_f(ws[16 + b]);
    const float inv = 1.0f / (mx - mn + 1e-7f);

    const float* xb = x + (size_t)b * (H_ * W_ * C_);
    float* ob = out + (size_t)b * (H_ * W_ * C_);

    float4 stash[6][3];   // statically indexed (unrolled p, unrolled cc)
    float4 oacc[2][4];    // [k][cc] output accumulators

#pragma unroll
    for (int cc = 0; cc < 4; ++cc) {

        __syncthreads();   // protect SAT from previous iteration's consumers

        // ---- P0: (cc==0) load full 64B half-line, scale, stash 3 quads;
        //          (cc>0) replay from stash. Then horizontal inclusive
        //          shuffle-scan, write exclusive H-prefix. ----
#pragma unroll
        for (int p = 0; p < 6; ++p) {
            const int rr = wv + 8 * p;
            if (rr < RG) {
                float4 v;
                if (cc == 0) {
                    const int gh = th0 - 7 + rr;
                    const int gw = tw0 - 7 + lane;
                    float4 q0 = make_float4(0.f, 0.f, 0.f, 0.f);
                    float4 q1 = q0, q2 = q0, q3 = q0;
                    if (lane < RG && gh >= 0 && gh < H_ && gw >= 0 && gw < W_) {
                        const float4* p4 = (const float4*)(xb +
                            ((size_t)(gh * W_ + gw)) * C_ + s * 16);
                        q0 = p4[0]; q1 = p4[1]; q2 = p4[2]; q3 = p4[3];
                        SC4(q0); SC4(q1); SC4(q2); SC4(q3);
                    }
                    v = q0;
                    stash[p][0] = q1; stash[p][1] = q2; stash[p][2] = q3;
                } else {
                    v = stash[p][cc - 1];
                }
#pragma unroll
                for (int off = 1; off < 64; off <<= 1) {
                    float nx = __shfl_up(v.x, off);
                    float ny = __shfl_up(v.y, off);
                    float nz = __shfl_up(v.z, off);
                    float nw = __shfl_up(v.w, off);
                    if (lane >= off) { v.x += nx; v.y += ny; v.z += nz; v.w += nw; }
                }
                if (lane < RG) SAT[rr][lane + 1] = v;
                else if (lane == 63) SAT[rr][0] = make_float4(0.f, 0.f, 0.f, 0.f);
            }
        }
        __syncthreads();

        // ---- P1: in-place exclusive vertical scan, one thread per SCALAR
        //          column (192 threads = 3 waves; consecutive tids hit
        //          consecutive banks -> 2-way aliasing per wave = free) ----
        if (tid < SR * 4) {
            float* col = (float*)SAT + tid;   // [48][192] scalar view
            float accv = 0.f;
#pragma unroll
            for (int r = 0; r < SR; ++r) {
                const float t = (r < RG) ? col[r * (SR * 4)] : 0.f;
                col[r * (SR * 4)] = accv;
                accv += t;
            }
        }
        __syncthreads();

        // ---- P2: consume all 4 scales from SAT corners, BN, accumulate ----
        const int ch0 = s * 16 + cc * 4;
        const float4 g4  = *(const float4*)(gamma + ch0);
        const float4 be4 = *(const float4*)(beta  + ch0);
        const float4 mm4 = *(const float4*)(mmean + ch0);
        const float4 mv4 = *(const float4*)(mvar  + ch0);
        const float bs0 = g4.x * rsqrtf(mv4.x + 1e-3f);
        const float bs1 = g4.y * rsqrtf(mv4.y + 1e-3f);
        const float bs2 = g4.z * rsqrtf(mv4.z + 1e-3f);
        const float bs3 = g4.w * rsqrtf(mv4.w + 1e-3f);
#pragma unroll
        for (int k = 0; k < 2; ++k) {
            const int j = k * 512 + tid;
            const int hl = j >> 5, wl = j & 31;
            float4 bx;
            // scale 2: rows hl+7..hl+8, cols wl+7..wl+8
            BOX(7, 2, bx);
            float ax = -0.3f * LG(bx.x);
            float ay = -0.3f * LG(bx.y);
            float az = -0.3f * LG(bx.z);
            float aw = -0.3f * LG(bx.w);
            // scale 4: rows hl+6..hl+9
            BOX(6, 4, bx);
            ax -= 0.1f * LG(bx.x);
            ay -= 0.1f * LG(bx.y);
            az -= 0.1f * LG(bx.z);
            aw -= 0.1f * LG(bx.w);
            // scale 8: rows hl+4..hl+11
            BOX(4, 8, bx);
            ax += 0.1f * LG(bx.x);
            ay += 0.1f * LG(bx.y);
            az += 0.1f * LG(bx.z);
            aw += 0.1f * LG(bx.w);
            // scale 16: rows hl..hl+15
            BOX(0, 16, bx);
            ax += 0.3f * LG(bx.x);
            ay += 0.3f * LG(bx.y);
            az += 0.3f * LG(bx.z);
            aw += 0.3f * LG(bx.w);

            float4 o4;
            o4.x = (ax - mm4.x) * bs0 + be4.x;
            o4.y = (ay - mm4.y) * bs1 + be4.y;
            o4.z = (az - mm4.z) * bs2 + be4.z;
            o4.w = (aw - mm4.w) * bs3 + be4.w;
            oacc[k][cc] = o4;
        }
    }

    // ---- final: one contiguous 64B store per pixel (full sector) ----
#pragma unroll
    for (int k = 0; k < 2; ++k) {
        const int j = k * 512 + tid;
        const int hl = j >> 5, wl = j & 31;
        float* dst = ob + ((size_t)((th0 + hl) * W_ + (tw0 + wl))) * C_ + s * 16;
        *(float4*)(dst + 0)  = oacc[k][0];
        *(float4*)(dst + 4)  = oacc[k][1];
        *(float4*)(dst + 8)  = oacc[k][2];
        *(float4*)(dst + 12) = oacc[k][3];
    }
}

extern "C" void kernel_launch(void* const* d_in, const int* in_sizes, int n_in,
                              void* d_out, int out_size, void* d_ws, size_t ws_size,
                              hipStream_t stream) {
    const float* x     = (const float*)d_in[0];
    const float* gamma = (const float*)d_in[1];
    const float* beta  = (const float*)d_in[2];
    const float* mmean = (const float*)d_in[3];
    const float* mvar  = (const float*)d_in[4];
    float* out = (float*)d_out;
    unsigned int* ws = (unsigned int*)d_ws;

    hipLaunchKernelGGL(init_ws, dim3(1), dim3(64), 0, stream, ws);
    hipLaunchKernelGGL(minmax_kernel, dim3(16, 64), dim3(256), 0, stream, x, ws);
    hipLaunchKernelGGL(lss_kernel, dim3(98 * 16), dim3(512), 0, stream,
                       x, gamma, beta, mmean, mvar, ws, out);
}

// Round 4
// 330.473 us; speedup vs baseline: 2.4168x; 2.4168x over previous
//
#include <hip/hip_runtime.h>
#include <cstdint>

#define B_ 16
#define H_ 224
#define W_ 224
#define C_ 32
#define TS 32      // output tile 32x32, 224 = 7*32
#define RG 47      // data rows/cols in halo region (32 + 7 top + 8 bottom)
#define SR 48      // SAT dim: exclusive 2D prefix needs +1 row & col

// ---- order-preserving float<->uint encoding for atomic min/max ----
__device__ __forceinline__ unsigned int enc_f(float f) {
    unsigned int u = __float_as_uint(f);
    return (u & 0x80000000u) ? ~u : (u | 0x80000000u);
}
__device__ __forceinline__ float dec_f(unsigned int u) {
    u = (u & 0x80000000u) ? (u & 0x7FFFFFFFu) : ~u;
    return __uint_as_float(u);
}

__global__ void init_ws(unsigned int* __restrict__ ws) {
    int t = threadIdx.x;
    if (t < 16) ws[t] = 0xFFFFFFFFu;
    else if (t < 32) ws[t] = 0u;
}

__global__ __launch_bounds__(256) void minmax_kernel(const float* __restrict__ x,
                                                     unsigned int* __restrict__ ws) {
    const int b = blockIdx.x;
    const int chunk = blockIdx.y;
    const int chunkElems = (H_ * W_ * C_) / 64;
    const float4* p = (const float4*)(x + (size_t)b * (H_ * W_ * C_) +
                                      (size_t)chunk * chunkElems);
    const int n4 = chunkElems / 4;
    float mn = 3.4e38f, mx = -3.4e38f;
    for (int i = threadIdx.x; i < n4; i += 256) {
        float4 v = p[i];
        mn = fminf(mn, fminf(fminf(v.x, v.y), fminf(v.z, v.w)));
        mx = fmaxf(mx, fmaxf(fmaxf(v.x, v.y), fmaxf(v.z, v.w)));
    }
#pragma unroll
    for (int off = 32; off > 0; off >>= 1) {
        mn = fminf(mn, __shfl_down(mn, off));
        mx = fmaxf(mx, __shfl_down(mx, off));
    }
    __shared__ float smn[4], smx[4];
    const int lane = threadIdx.x & 63, wv = threadIdx.x >> 6;
    if (lane == 0) { smn[wv] = mn; smx[wv] = mx; }
    __syncthreads();
    if (threadIdx.x == 0) {
        mn = fminf(fminf(smn[0], smn[1]), fminf(smn[2], smn[3]));
        mx = fmaxf(fmaxf(smx[0], smx[1]), fmaxf(smx[2], smx[3]));
        atomicMin(&ws[b], enc_f(mn));
        atomicMax(&ws[16 + b], enc_f(mx));
    }
}

// Round-4 structure: ONE pass over all 16 channels of the split.
// 4 float4 SAT planes live in LDS simultaneously (147,456 B); each block
// reads its full 64B half-line exactly once (P0) and writes its output
// half-line exactly once (P2). NO register array crosses a barrier
// (round-3 scratch lesson / rule #20): P0 quads are consumed immediately,
// P2 uses macro-expanded named variables per quad.
#define LG(v) __log2f(fmaxf((v), 0.0f) + 1e-7f)

#define BOX(S, o, sc, bx) {                                              \
        float4 q00 = S[hl + (o)][wl + (o)];                              \
        float4 q01 = S[hl + (o)][wl + (o) + (sc)];                       \
        float4 q10 = S[hl + (o) + (sc)][wl + (o)];                       \
        float4 q11 = S[hl + (o) + (sc)][wl + (o) + (sc)];                \
        bx.x = q11.x - q01.x - q10.x + q00.x;                            \
        bx.y = q11.y - q01.y - q10.y + q00.y;                            \
        bx.z = q11.z - q01.z - q10.z + q00.z;                            \
        bx.w = q11.w - q01.w - q10.w + q00.w; }

#define SC4(q) { q.x = (q.x - mn) * inv; q.y = (q.y - mn) * inv;         \
                 q.z = (q.z - mn) * inv; q.w = (q.w - mn) * inv; }

// full per-quad consume: 4 scales from SAT corners + BN -> named o4
#define DOQUAD(qi, o4) {                                                 \
        const int ch0 = s * 16 + (qi) * 4;                               \
        const float4 (*S)[SR] = SAT[qi];                                 \
        float4 bx;                                                       \
        BOX(S, 7, 2, bx);                                                \
        float ax = -0.3f * LG(bx.x);                                     \
        float ay = -0.3f * LG(bx.y);                                     \
        float az = -0.3f * LG(bx.z);                                     \
        float aw = -0.3f * LG(bx.w);                                     \
        BOX(S, 6, 4, bx);                                                \
        ax -= 0.1f * LG(bx.x); ay -= 0.1f * LG(bx.y);                    \
        az -= 0.1f * LG(bx.z); aw -= 0.1f * LG(bx.w);                    \
        BOX(S, 4, 8, bx);                                                \
        ax += 0.1f * LG(bx.x); ay += 0.1f * LG(bx.y);                    \
        az += 0.1f * LG(bx.z); aw += 0.1f * LG(bx.w);                    \
        BOX(S, 0, 16, bx);                                               \
        ax += 0.3f * LG(bx.x); ay += 0.3f * LG(bx.y);                    \
        az += 0.3f * LG(bx.z); aw += 0.3f * LG(bx.w);                    \
        const float4 g4  = *(const float4*)(gamma + ch0);                \
        const float4 be4 = *(const float4*)(beta  + ch0);                \
        const float4 mm4 = *(const float4*)(mmean + ch0);                \
        const float4 mv4 = *(const float4*)(mvar  + ch0);                \
        o4.x = (ax - mm4.x) * (g4.x * rsqrtf(mv4.x + 1e-3f)) + be4.x;    \
        o4.y = (ay - mm4.y) * (g4.y * rsqrtf(mv4.y + 1e-3f)) + be4.y;    \
        o4.z = (az - mm4.z) * (g4.z * rsqrtf(mv4.z + 1e-3f)) + be4.z;    \
        o4.w = (aw - mm4.w) * (g4.w * rsqrtf(mv4.w + 1e-3f)) + be4.w; }

__device__ __forceinline__ void hscan(float4& v, int lane) {
#pragma unroll
    for (int off = 1; off < 64; off <<= 1) {
        float nx = __shfl_up(v.x, off);
        float ny = __shfl_up(v.y, off);
        float nz = __shfl_up(v.z, off);
        float nw = __shfl_up(v.w, off);
        if (lane >= off) { v.x += nx; v.y += ny; v.z += nz; v.w += nw; }
    }
}

__global__ __launch_bounds__(1024, 4) void lss_kernel(
    const float* __restrict__ x,
    const float* __restrict__ gamma, const float* __restrict__ beta,
    const float* __restrict__ mmean, const float* __restrict__ mvar,
    const unsigned int* __restrict__ ws,
    float* __restrict__ out)
{
    __shared__ float4 SAT[4][SR][SR];   // 147,456 B -> 1 block/CU, 16 waves

    const int bi = blockIdx.x;
    const int grp = bi >> 4, wi = bi & 15;
    const int s = (wi >> 3) & 1;           // channel half: ch s*16 .. s*16+15
    const int tile = grp * 8 + (wi & 7);   // splits of a tile stay adjacent
    const int b = tile / 49;
    const int t2 = tile - b * 49;
    const int th0 = (t2 / 7) * TS;
    const int tw0 = (t2 % 7) * TS;
    const int tid = threadIdx.x;
    const int lane = tid & 63, wv = tid >> 6;   // 16 waves

    const float mn = dec_f(ws[b]);
    const float mx = dec_f(ws[16 + b]);
    const float inv = 1.0f / (mx - mn + 1e-7f);

    const float* xb = x + (size_t)b * (H_ * W_ * C_);
    float* ob = out + (size_t)b * (H_ * W_ * C_);

    // ---- P0: load full 64B half-line once, scale, h-scan 4 quads,
    //          write exclusive H-prefix into 4 SAT planes ----
#pragma unroll
    for (int p = 0; p < 3; ++p) {
        const int rr = wv + 16 * p;
        if (rr < RG) {
            const int gh = th0 - 7 + rr;
            const int gw = tw0 - 7 + lane;
            float4 q0 = make_float4(0.f, 0.f, 0.f, 0.f);
            float4 q1 = q0, q2 = q0, q3 = q0;
            if (lane < RG && gh >= 0 && gh < H_ && gw >= 0 && gw < W_) {
                const float4* p4 = (const float4*)(xb +
                    ((size_t)(gh * W_ + gw)) * C_ + s * 16);
                q0 = p4[0]; q1 = p4[1]; q2 = p4[2]; q3 = p4[3];
                SC4(q0); SC4(q1); SC4(q2); SC4(q3);
            }
            hscan(q0, lane); hscan(q1, lane); hscan(q2, lane); hscan(q3, lane);
            if (lane < RG) {
                SAT[0][rr][lane + 1] = q0;
                SAT[1][rr][lane + 1] = q1;
                SAT[2][rr][lane + 1] = q2;
                SAT[3][rr][lane + 1] = q3;
            } else if (lane == 63) {
                const float4 z = make_float4(0.f, 0.f, 0.f, 0.f);
                SAT[0][rr][0] = z; SAT[1][rr][0] = z;
                SAT[2][rr][0] = z; SAT[3][rr][0] = z;
            }
        }
    }
    __syncthreads();

    // ---- P1: in-place exclusive vertical scan. 768 scalar columns
    //          (192 per plane); waves 3,7,11,15 idle (wave-aligned).
    //          Consecutive tids -> consecutive banks (2-way = free). ----
    {
        const int q = tid >> 8;        // plane 0..3
        const int c = tid & 255;       // scalar column within plane
        if (c < 192) {
            float* col = (float*)&SAT[q][0][0] + c;
            float accv = 0.f;
#pragma unroll
            for (int r = 0; r < SR; ++r) {
                const float t = (r < RG) ? col[r * 192] : 0.f;
                col[r * 192] = accv;
                accv += t;
            }
        }
    }
    __syncthreads();

    // ---- P2: one thread per output pixel; consume 4 planes x 4 scales,
    //          BN, single contiguous 64B store ----
    {
        const int hl = tid >> 5, wl = tid & 31;
        float4 o0, o1, o2, o3;
        DOQUAD(0, o0);
        DOQUAD(1, o1);
        DOQUAD(2, o2);
        DOQUAD(3, o3);
        float* dst = ob + ((size_t)((th0 + hl) * W_ + (tw0 + wl))) * C_ + s * 16;
        *(float4*)(dst + 0)  = o0;
        *(float4*)(dst + 4)  = o1;
        *(float4*)(dst + 8)  = o2;
        *(float4*)(dst + 12) = o3;
    }
}

extern "C" void kernel_launch(void* const* d_in, const int* in_sizes, int n_in,
                              void* d_out, int out_size, void* d_ws, size_t ws_size,
                              hipStream_t stream) {
    const float* x     = (const float*)d_in[0];
    const float* gamma = (const float*)d_in[1];
    const float* beta  = (const float*)d_in[2];
    const float* mmean = (const float*)d_in[3];
    const float* mvar  = (const float*)d_in[4];
    float* out = (float*)d_out;
    unsigned int* ws = (unsigned int*)d_ws;

    hipLaunchKernelGGL(init_ws, dim3(1), dim3(64), 0, stream, ws);
    hipLaunchKernelGGL(minmax_kernel, dim3(16, 64), dim3(256), 0, stream, x, ws);
    hipLaunchKernelGGL(lss_kernel, dim3(98 * 16), dim3(1024), 0, stream,
                       x, gamma, beta, mmean, mvar, ws, out);
}

// Round 5
// 283.676 us; speedup vs baseline: 2.8155x; 1.1650x over previous
//
#include <hip/hip_runtime.h>
#include <cstdint>

#define B_ 16
#define H_ 224
#define W_ 224
#define C_ 32
#define TS 32      // output tile 32x32, 224 = 7*32
#define RG 47      // data rows/cols in halo region (32 + 7 top + 8 bottom)
#define SR 48      // SAT dim: exclusive 2D prefix needs +1 row & col

// ---- order-preserving float<->uint encoding for atomic min/max ----
__device__ __forceinline__ unsigned int enc_f(float f) {
    unsigned int u = __float_as_uint(f);
    return (u & 0x80000000u) ? ~u : (u | 0x80000000u);
}
__device__ __forceinline__ float dec_f(unsigned int u) {
    u = (u & 0x80000000u) ? (u & 0x7FFFFFFFu) : ~u;
    return __uint_as_float(u);
}

__global__ void init_ws(unsigned int* __restrict__ ws) {
    int t = threadIdx.x;
    if (t < 16) ws[t] = 0xFFFFFFFFu;
    else if (t < 32) ws[t] = 0u;
}

__global__ __launch_bounds__(256) void minmax_kernel(const float* __restrict__ x,
                                                     unsigned int* __restrict__ ws) {
    const int b = blockIdx.x;
    const int chunk = blockIdx.y;
    const int chunkElems = (H_ * W_ * C_) / 64;
    const float4* p = (const float4*)(x + (size_t)b * (H_ * W_ * C_) +
                                      (size_t)chunk * chunkElems);
    const int n4 = chunkElems / 4;
    float mn = 3.4e38f, mx = -3.4e38f;
    for (int i = threadIdx.x; i < n4; i += 256) {
        float4 v = p[i];
        mn = fminf(mn, fminf(fminf(v.x, v.y), fminf(v.z, v.w)));
        mx = fmaxf(mx, fmaxf(fmaxf(v.x, v.y), fmaxf(v.z, v.w)));
    }
#pragma unroll
    for (int off = 32; off > 0; off >>= 1) {
        mn = fminf(mn, __shfl_down(mn, off));
        mx = fmaxf(mx, __shfl_down(mx, off));
    }
    __shared__ float smn[4], smx[4];
    const int lane = threadIdx.x & 63, wv = threadIdx.x >> 6;
    if (lane == 0) { smn[wv] = mn; smx[wv] = mx; }
    __syncthreads();
    if (threadIdx.x == 0) {
        mn = fminf(fminf(smn[0], smn[1]), fminf(smn[2], smn[3]));
        mx = fmaxf(fmaxf(smx[0], smx[1]), fmaxf(smx[2], smx[3]));
        atomicMin(&ws[b], enc_f(mn));
        atomicMax(&ws[16 + b], enc_f(mx));
    }
}

// Round-5 change: the horizontal scan uses the gfx9 DPP wave64 inclusive-scan
// idiom (row_shr 1/2/4/8 + row_bcast15/31) — pure VALU v_add_f32_dpp, zero
// LDS-pipe traffic. Round 4's __shfl_up compiled to ds_bpermute: ~4.5k DS ops
// per block (~25k LDS-pipe cycles) which was the measured bottleneck.
template<int CTRL, int MASK>
__device__ __forceinline__ float dpp_add(float x) {
    // update_dpp(old=0, src=x): lanes with invalid source (or masked rows)
    // contribute the identity 0 — no predication needed.
    int t = __builtin_amdgcn_update_dpp(0, (int)__float_as_uint(x),
                                        CTRL, MASK, 0xf, false);
    return x + __uint_as_float((unsigned)t);
}
template<int CTRL, int MASK>
__device__ __forceinline__ void dpp_step4(float4& v) {
    v.x = dpp_add<CTRL, MASK>(v.x);
    v.y = dpp_add<CTRL, MASK>(v.y);
    v.z = dpp_add<CTRL, MASK>(v.z);
    v.w = dpp_add<CTRL, MASK>(v.w);
}
__device__ __forceinline__ void hscan(float4& v) {
    dpp_step4<0x111, 0xf>(v);   // row_shr:1
    dpp_step4<0x112, 0xf>(v);   // row_shr:2
    dpp_step4<0x114, 0xf>(v);   // row_shr:4
    dpp_step4<0x118, 0xf>(v);   // row_shr:8  -> inclusive scan per 16-lane row
    dpp_step4<0x142, 0xa>(v);   // row_bcast15 into rows 1,3
    dpp_step4<0x143, 0xc>(v);   // row_bcast31 into rows 2,3
}

#define LG(v) __log2f(fmaxf((v), 0.0f) + 1e-7f)

#define BOX(S, o, sc, bx) {                                              \
        float4 q00 = S[hl + (o)][wl + (o)];                              \
        float4 q01 = S[hl + (o)][wl + (o) + (sc)];                       \
        float4 q10 = S[hl + (o) + (sc)][wl + (o)];                       \
        float4 q11 = S[hl + (o) + (sc)][wl + (o) + (sc)];                \
        bx.x = q11.x - q01.x - q10.x + q00.x;                            \
        bx.y = q11.y - q01.y - q10.y + q00.y;                            \
        bx.z = q11.z - q01.z - q10.z + q00.z;                            \
        bx.w = q11.w - q01.w - q10.w + q00.w; }

#define SC4(q) { q.x = (q.x - mn) * inv; q.y = (q.y - mn) * inv;         \
                 q.z = (q.z - mn) * inv; q.w = (q.w - mn) * inv; }

// full per-quad consume: 4 scales from SAT corners + BN -> named o4
#define DOQUAD(qi, o4) {                                                 \
        const int ch0 = s * 16 + (qi) * 4;                               \
        const float4 (*S)[SR] = SAT[qi];                                 \
        float4 bx;                                                       \
        BOX(S, 7, 2, bx);                                                \
        float ax = -0.3f * LG(bx.x);                                     \
        float ay = -0.3f * LG(bx.y);                                     \
        float az = -0.3f * LG(bx.z);                                     \
        float aw = -0.3f * LG(bx.w);                                     \
        BOX(S, 6, 4, bx);                                                \
        ax -= 0.1f * LG(bx.x); ay -= 0.1f * LG(bx.y);                    \
        az -= 0.1f * LG(bx.z); aw -= 0.1f * LG(bx.w);                    \
        BOX(S, 4, 8, bx);                                                \
        ax += 0.1f * LG(bx.x); ay += 0.1f * LG(bx.y);                    \
        az += 0.1f * LG(bx.z); aw += 0.1f * LG(bx.w);                    \
        BOX(S, 0, 16, bx);                                               \
        ax += 0.3f * LG(bx.x); ay += 0.3f * LG(bx.y);                    \
        az += 0.3f * LG(bx.z); aw += 0.3f * LG(bx.w);                    \
        const float4 g4  = *(const float4*)(gamma + ch0);                \
        const float4 be4 = *(const float4*)(beta  + ch0);                \
        const float4 mm4 = *(const float4*)(mmean + ch0);                \
        const float4 mv4 = *(const float4*)(mvar  + ch0);                \
        o4.x = (ax - mm4.x) * (g4.x * rsqrtf(mv4.x + 1e-3f)) + be4.x;    \
        o4.y = (ay - mm4.y) * (g4.y * rsqrtf(mv4.y + 1e-3f)) + be4.y;    \
        o4.z = (az - mm4.z) * (g4.z * rsqrtf(mv4.z + 1e-3f)) + be4.z;    \
        o4.w = (aw - mm4.w) * (g4.w * rsqrtf(mv4.w + 1e-3f)) + be4.w; }

__global__ __launch_bounds__(1024, 4) void lss_kernel(
    const float* __restrict__ x,
    const float* __restrict__ gamma, const float* __restrict__ beta,
    const float* __restrict__ mmean, const float* __restrict__ mvar,
    const unsigned int* __restrict__ ws,
    float* __restrict__ out)
{
    __shared__ float4 SAT[4][SR][SR];   // 147,456 B -> 1 block/CU, 16 waves

    const int bi = blockIdx.x;
    const int grp = bi >> 4, wi = bi & 15;
    const int s = (wi >> 3) & 1;           // channel half: ch s*16 .. s*16+15
    const int tile = grp * 8 + (wi & 7);   // splits of a tile stay adjacent
    const int b = tile / 49;
    const int t2 = tile - b * 49;
    const int th0 = (t2 / 7) * TS;
    const int tw0 = (t2 % 7) * TS;
    const int tid = threadIdx.x;
    const int lane = tid & 63, wv = tid >> 6;   // 16 waves

    const float mn = dec_f(ws[b]);
    const float mx = dec_f(ws[16 + b]);
    const float inv = 1.0f / (mx - mn + 1e-7f);

    const float* xb = x + (size_t)b * (H_ * W_ * C_);
    float* ob = out + (size_t)b * (H_ * W_ * C_);

    // ---- P0: load full 64B half-line once, scale, DPP h-scan 4 quads,
    //          write exclusive H-prefix into 4 SAT planes ----
#pragma unroll
    for (int p = 0; p < 3; ++p) {
        const int rr = wv + 16 * p;
        if (rr < RG) {
            const int gh = th0 - 7 + rr;
            const int gw = tw0 - 7 + lane;
            float4 q0 = make_float4(0.f, 0.f, 0.f, 0.f);
            float4 q1 = q0, q2 = q0, q3 = q0;
            if (lane < RG && gh >= 0 && gh < H_ && gw >= 0 && gw < W_) {
                const float4* p4 = (const float4*)(xb +
                    ((size_t)(gh * W_ + gw)) * C_ + s * 16);
                q0 = p4[0]; q1 = p4[1]; q2 = p4[2]; q3 = p4[3];
                SC4(q0); SC4(q1); SC4(q2); SC4(q3);
            }
            hscan(q0); hscan(q1); hscan(q2); hscan(q3);
            if (lane < RG) {
                SAT[0][rr][lane + 1] = q0;
                SAT[1][rr][lane + 1] = q1;
                SAT[2][rr][lane + 1] = q2;
                SAT[3][rr][lane + 1] = q3;
            } else if (lane == 63) {
                const float4 z = make_float4(0.f, 0.f, 0.f, 0.f);
                SAT[0][rr][0] = z; SAT[1][rr][0] = z;
                SAT[2][rr][0] = z; SAT[3][rr][0] = z;
            }
        }
    }
    __syncthreads();

    // ---- P1: in-place exclusive vertical scan. 768 scalar columns
    //          (192 per plane); waves 3,7,11,15 idle (wave-aligned).
    //          Consecutive tids -> consecutive banks (2-way = free). ----
    {
        const int q = tid >> 8;        // plane 0..3
        const int c = tid & 255;       // scalar column within plane
        if (c < 192) {
            float* col = (float*)&SAT[q][0][0] + c;
            float accv = 0.f;
#pragma unroll
            for (int r = 0; r < SR; ++r) {
                const float t = (r < RG) ? col[r * 192] : 0.f;
                col[r * 192] = accv;
                accv += t;
            }
        }
    }
    __syncthreads();

    // ---- P2: one thread per output pixel; consume 4 planes x 4 scales,
    //          BN, single contiguous 64B store ----
    {
        const int hl = tid >> 5, wl = tid & 31;
        float4 o0, o1, o2, o3;
        DOQUAD(0, o0);
        DOQUAD(1, o1);
        DOQUAD(2, o2);
        DOQUAD(3, o3);
        float* dst = ob + ((size_t)((th0 + hl) * W_ + (tw0 + wl))) * C_ + s * 16;
        *(float4*)(dst + 0)  = o0;
        *(float4*)(dst + 4)  = o1;
        *(float4*)(dst + 8)  = o2;
        *(float4*)(dst + 12) = o3;
    }
}

extern "C" void kernel_launch(void* const* d_in, const int* in_sizes, int n_in,
                              void* d_out, int out_size, void* d_ws, size_t ws_size,
                              hipStream_t stream) {
    const float* x     = (const float*)d_in[0];
    const float* gamma = (const float*)d_in[1];
    const float* beta  = (const float*)d_in[2];
    const float* mmean = (const float*)d_in[3];
    const float* mvar  = (const float*)d_in[4];
    float* out = (float*)d_out;
    unsigned int* ws = (unsigned int*)d_ws;

    hipLaunchKernelGGL(init_ws, dim3(1), dim3(64), 0, stream, ws);
    hipLaunchKernelGGL(minmax_kernel, dim3(16, 64), dim3(256), 0, stream, x, ws);
    hipLaunchKernelGGL(lss_kernel, dim3(98 * 16), dim3(1024), 0, stream,
                       x, gamma, beta, mmean, mvar, ws, out);
}

// Round 6
// 265.839 us; speedup vs baseline: 3.0044x; 1.0671x over previous
//
#include <hip/hip_runtime.h>
#include <cstdint>

#define B_ 16
#define H_ 224
#define W_ 224
#define C_ 32
#define TS 32      // output tile 32x32, 224 = 7*32
#define RG 47      // data rows/cols in halo region (32 + 7 top + 8 bottom)
#define SR 48      // SAT dim: exclusive 2D prefix needs +1 row & col

// ---- order-preserving float<->uint encoding (atomic fallback path) ----
__device__ __forceinline__ unsigned int enc_f(float f) {
    unsigned int u = __float_as_uint(f);
    return (u & 0x80000000u) ? ~u : (u | 0x80000000u);
}
__device__ __forceinline__ float dec_f(unsigned int u) {
    u = (u & 0x80000000u) ? (u & 0x7FFFFFFFu) : ~u;
    return __uint_as_float(u);
}

__global__ void init_ws(unsigned int* __restrict__ ws) {
    int t = threadIdx.x;
    if (t < 16) ws[t] = 0xFFFFFFFFu;
    else if (t < 32) ws[t] = 0u;
}

// common block-level min/max reduction over this block's chunk
__device__ __forceinline__ void blk_minmax(const float* __restrict__ x,
                                           float& mn, float& mx) {
    const int b = blockIdx.x;
    const int chunk = blockIdx.y;
    const int chunkElems = (H_ * W_ * C_) / 64;
    const float4* p = (const float4*)(x + (size_t)b * (H_ * W_ * C_) +
                                      (size_t)chunk * chunkElems);
    const int n4 = chunkElems / 4;
    mn = 3.4e38f; mx = -3.4e38f;
    for (int i = threadIdx.x; i < n4; i += 256) {
        float4 v = p[i];
        mn = fminf(mn, fminf(fminf(v.x, v.y), fminf(v.z, v.w)));
        mx = fmaxf(mx, fmaxf(fmaxf(v.x, v.y), fmaxf(v.z, v.w)));
    }
#pragma unroll
    for (int off = 32; off > 0; off >>= 1) {
        mn = fminf(mn, __shfl_down(mn, off));
        mx = fmaxf(mx, __shfl_down(mx, off));
    }
    __shared__ float smn[4], smx[4];
    const int lane = threadIdx.x & 63, wv = threadIdx.x >> 6;
    if (lane == 0) { smn[wv] = mn; smx[wv] = mx; }
    __syncthreads();
    mn = fminf(fminf(smn[0], smn[1]), fminf(smn[2], smn[3]));
    mx = fmaxf(fmaxf(smx[0], smx[1]), fmaxf(smx[2], smx[3]));
}

// slot version: no init kernel, no atomics; block (b,chunk) owns its slot
__global__ __launch_bounds__(256) void minmax_slots(const float* __restrict__ x,
                                                    float* __restrict__ wsf) {
    float mn, mx;
    blk_minmax(x, mn, mx);
    if (threadIdx.x == 0) {
        wsf[blockIdx.y * 16 + blockIdx.x] = mn;
        wsf[1024 + blockIdx.y * 16 + blockIdx.x] = mx;
    }
}

// atomic fallback (ws too small for slots)
__global__ __launch_bounds__(256) void minmax_atomic(const float* __restrict__ x,
                                                     unsigned int* __restrict__ ws) {
    float mn, mx;
    blk_minmax(x, mn, mx);
    if (threadIdx.x == 0) {
        atomicMin(&ws[blockIdx.x], enc_f(mn));
        atomicMax(&ws[16 + blockIdx.x], enc_f(mx));
    }
}

// DPP wave64 inclusive scan (row_shr 1/2/4/8 + row_bcast15/31) — pure VALU
template<int CTRL, int MASK>
__device__ __forceinline__ float dpp_add(float x) {
    int t = __builtin_amdgcn_update_dpp(0, (int)__float_as_uint(x),
                                        CTRL, MASK, 0xf, false);
    return x + __uint_as_float((unsigned)t);
}
template<int CTRL, int MASK>
__device__ __forceinline__ void dpp_step4(float4& v) {
    v.x = dpp_add<CTRL, MASK>(v.x);
    v.y = dpp_add<CTRL, MASK>(v.y);
    v.z = dpp_add<CTRL, MASK>(v.z);
    v.w = dpp_add<CTRL, MASK>(v.w);
}
__device__ __forceinline__ void hscan(float4& v) {
    dpp_step4<0x111, 0xf>(v);   // row_shr:1
    dpp_step4<0x112, 0xf>(v);   // row_shr:2
    dpp_step4<0x114, 0xf>(v);   // row_shr:4
    dpp_step4<0x118, 0xf>(v);   // row_shr:8
    dpp_step4<0x142, 0xa>(v);   // row_bcast15 -> rows 1,3
    dpp_step4<0x143, 0xc>(v);   // row_bcast31 -> rows 2,3
}

#define CL(a) (fmaxf((a), 0.0f) + 1e-7f)

#define BOXD(S, o, sc, bx) {                                             \
        float4 q00 = S[hl + (o)][wl + (o)];                              \
        float4 q01 = S[hl + (o)][wl + (o) + (sc)];                       \
        float4 q10 = S[hl + (o) + (sc)][wl + (o)];                       \
        float4 q11 = S[hl + (o) + (sc)][wl + (o) + (sc)];                \
        bx.x = q11.x - q01.x - q10.x + q00.x;                            \
        bx.y = q11.y - q01.y - q10.y + q00.y;                            \
        bx.z = q11.z - q01.z - q10.z + q00.z;                            \
        bx.w = q11.w - q01.w - q10.w + q00.w; }

// combined-log per component: alpha = 0.1*(log2(m16^3*m8) - log2(m2^3*m4));
// the 0.1 and BN fold into one fma: out = L*(0.1*t) + (beta - mm*t)
#define LSSCOMP(comp, OUT) {                                             \
        const float tq = g4.comp * rsqrtf(mv4.comp + 1e-3f);             \
        const float wq = 0.1f * tq;                                      \
        const float oq = be4.comp - mm4.comp * tq;                       \
        const float a2 = CL(b2.comp),  a4 = CL(b4.comp);                 \
        const float a8 = CL(b8.comp),  a16 = CL(b16.comp);               \
        const float Lq = __log2f(a16 * a16 * a16 * a8)                   \
                       - __log2f(a2 * a2 * a2 * a4);                     \
        OUT = fmaf(Lq, wq, oq); }

#define DOQUAD(qi, o4) {                                                 \
        const int ch0 = chbase + (qi) * 4;                               \
        const float4 (*S)[SR] = SAT[qi];                                 \
        float4 b2, b4, b8, b16;                                          \
        BOXD(S, 7, 2, b2);                                               \
        BOXD(S, 6, 4, b4);                                               \
        BOXD(S, 4, 8, b8);                                               \
        BOXD(S, 0, 16, b16);                                             \
        const float4 g4  = *(const float4*)(gamma + ch0);                \
        const float4 be4 = *(const float4*)(beta  + ch0);                \
        const float4 mm4 = *(const float4*)(mmean + ch0);                \
        const float4 mv4 = *(const float4*)(mvar  + ch0);                \
        LSSCOMP(x, o4.x); LSSCOMP(y, o4.y);                              \
        LSSCOMP(z, o4.z); LSSCOMP(w, o4.w); }

// Round-6: 512-thread blocks, 2 SAT planes (73,728 B LDS) -> 2 blocks/CU.
// Sibling (qp) blocks sit 16 apart in blockIdx (same XCD) so their 32B
// accesses to a shared 64B sector merge in L2. Phases of the two resident
// blocks desynchronize -> VALU-heavy P0 overlaps LDS-heavy P2.
template<bool SLOTS>
__global__ __launch_bounds__(512, 4) void lss_kernel(
    const float* __restrict__ x,
    const float* __restrict__ gamma, const float* __restrict__ beta,
    const float* __restrict__ mmean, const float* __restrict__ mvar,
    const unsigned int* __restrict__ ws,
    float* __restrict__ out)
{
    __shared__ float4 SAT[2][SR][SR];   // 73,728 B

    const int bi = blockIdx.x;
    const int grp = bi >> 5, wi = bi & 31;
    const int tile = grp * 8 + (wi & 7);
    const int s  = (wi >> 3) & 1;          // channel half
    const int qp = (wi >> 4) & 1;          // quad pair within half
    const int b = tile / 49;
    const int t2 = tile - b * 49;
    const int th0 = (t2 / 7) * TS;
    const int tw0 = (t2 % 7) * TS;
    const int tid = threadIdx.x;
    const int lane = tid & 63, wv = tid >> 6;   // 8 waves
    const int chbase = s * 16 + qp * 8;

    float mn, mx;
    if (SLOTS) {
        const float* wsf = (const float*)ws;
        mn = 3.4e38f; mx = -3.4e38f;
#pragma unroll
        for (int i = 0; i < 64; ++i) {      // uniform per block, L2-hot
            mn = fminf(mn, wsf[i * 16 + b]);
            mx = fmaxf(mx, wsf[1024 + i * 16 + b]);
        }
    } else {
        mn = dec_f(ws[b]);
        mx = dec_f(ws[16 + b]);
    }
    const float inv = 1.0f / (mx - mn + 1e-7f);
    const float nmi = -mn * inv;

    const float* xb = x + (size_t)b * (H_ * W_ * C_);
    float* ob = out + (size_t)b * (H_ * W_ * C_);

    // ---- P0: load 32B once, scale, DPP h-scan 2 quads, write excl H-prefix ----
#pragma unroll
    for (int p = 0; p < 6; ++p) {
        const int rr = wv + 8 * p;
        if (rr < RG) {
            const int gh = th0 - 7 + rr;
            const int gw = tw0 - 7 + lane;
            float4 q0 = make_float4(0.f, 0.f, 0.f, 0.f);
            float4 q1 = q0;
            if (lane < RG && gh >= 0 && gh < H_ && gw >= 0 && gw < W_) {
                const float4* p4 = (const float4*)(xb +
                    ((size_t)(gh * W_ + gw)) * C_ + chbase);
                q0 = p4[0]; q1 = p4[1];
                q0.x = fmaf(q0.x, inv, nmi); q0.y = fmaf(q0.y, inv, nmi);
                q0.z = fmaf(q0.z, inv, nmi); q0.w = fmaf(q0.w, inv, nmi);
                q1.x = fmaf(q1.x, inv, nmi); q1.y = fmaf(q1.y, inv, nmi);
                q1.z = fmaf(q1.z, inv, nmi); q1.w = fmaf(q1.w, inv, nmi);
            }
            hscan(q0); hscan(q1);
            if (lane < RG) {
                SAT[0][rr][lane + 1] = q0;
                SAT[1][rr][lane + 1] = q1;
            } else if (lane == 63) {
                const float4 z = make_float4(0.f, 0.f, 0.f, 0.f);
                SAT[0][rr][0] = z; SAT[1][rr][0] = z;
            }
        }
    }
    __syncthreads();

    // ---- P1: in-place exclusive vertical scan; 384 scalar columns
    //          (192/plane); consecutive tids -> consecutive banks ----
    {
        int q = -1, c = 0;
        if (tid < 192)      { q = 0; c = tid; }
        else if (tid < 384) { q = 1; c = tid - 192; }
        if (q >= 0) {
            float* col = (float*)&SAT[q][0][0] + c;
            float accv = 0.f;
#pragma unroll
            for (int r = 0; r < SR; ++r) {
                const float t = (r < RG) ? col[r * 192] : 0.f;
                col[r * 192] = accv;
                accv += t;
            }
        }
    }
    __syncthreads();

    // ---- P2: 2 pixels/thread; 2 planes x 4 scales from SAT corners,
    //          combined-log + fused BN, one 32B store per pixel ----
    {
        const int wl = tid & 31;
        const int hl0 = tid >> 5;             // 0..15
#pragma unroll
        for (int pp = 0; pp < 2; ++pp) {
            const int hl = hl0 + pp * 16;
            float4 o0, o1;
            DOQUAD(0, o0);
            DOQUAD(1, o1);
            float* dst = ob + ((size_t)((th0 + hl) * W_ + (tw0 + wl))) * C_ + chbase;
            *(float4*)(dst + 0) = o0;
            *(float4*)(dst + 4) = o1;
        }
    }
}

extern "C" void kernel_launch(void* const* d_in, const int* in_sizes, int n_in,
                              void* d_out, int out_size, void* d_ws, size_t ws_size,
                              hipStream_t stream) {
    const float* x     = (const float*)d_in[0];
    const float* gamma = (const float*)d_in[1];
    const float* beta  = (const float*)d_in[2];
    const float* mmean = (const float*)d_in[3];
    const float* mvar  = (const float*)d_in[4];
    float* out = (float*)d_out;
    unsigned int* ws = (unsigned int*)d_ws;

    if (ws_size >= 8192) {
        hipLaunchKernelGGL(minmax_slots, dim3(16, 64), dim3(256), 0, stream,
                           x, (float*)ws);
        hipLaunchKernelGGL((lss_kernel<true>), dim3(98 * 32), dim3(512), 0, stream,
                           x, gamma, beta, mmean, mvar, ws, out);
    } else {
        hipLaunchKernelGGL(init_ws, dim3(1), dim3(64), 0, stream, ws);
        hipLaunchKernelGGL(minmax_atomic, dim3(16, 64), dim3(256), 0, stream, x, ws);
        hipLaunchKernelGGL((lss_kernel<false>), dim3(98 * 32), dim3(512), 0, stream,
                           x, gamma, beta, mmean, mvar, ws, out);
    }
}

// Round 7
// 261.670 us; speedup vs baseline: 3.0523x; 1.0159x over previous
//
#include <hip/hip_runtime.h>
#include <cstdint>

#define B_ 16
#define H_ 224
#define W_ 224
#define C_ 32
#define TS 32      // output tile 32x32, 224 = 7*32
#define RG 47      // data rows/cols in halo region (32 + 7 top + 8 bottom)
#define SR 48      // SAT dim: exclusive 2D prefix needs +1 row & col
#define SP 49      // padded row stride (float4s): +4 banks/row, kills P2 aliasing

// ---- order-preserving float<->uint encoding (atomic fallback path) ----
__device__ __forceinline__ unsigned int enc_f(float f) {
    unsigned int u = __float_as_uint(f);
    return (u & 0x80000000u) ? ~u : (u | 0x80000000u);
}
__device__ __forceinline__ float dec_f(unsigned int u) {
    u = (u & 0x80000000u) ? (u & 0x7FFFFFFFu) : ~u;
    return __uint_as_float(u);
}

__global__ void init_ws(unsigned int* __restrict__ ws) {
    int t = threadIdx.x;
    if (t < 16) ws[t] = 0xFFFFFFFFu;
    else if (t < 32) ws[t] = 0u;
}

// common block-level min/max reduction over this block's chunk
__device__ __forceinline__ void blk_minmax(const float* __restrict__ x,
                                           float& mn, float& mx) {
    const int b = blockIdx.x;
    const int chunk = blockIdx.y;
    const int chunkElems = (H_ * W_ * C_) / 64;
    const float4* p = (const float4*)(x + (size_t)b * (H_ * W_ * C_) +
                                      (size_t)chunk * chunkElems);
    const int n4 = chunkElems / 4;
    mn = 3.4e38f; mx = -3.4e38f;
    for (int i = threadIdx.x; i < n4; i += 256) {
        float4 v = p[i];
        mn = fminf(mn, fminf(fminf(v.x, v.y), fminf(v.z, v.w)));
        mx = fmaxf(mx, fmaxf(fmaxf(v.x, v.y), fmaxf(v.z, v.w)));
    }
#pragma unroll
    for (int off = 32; off > 0; off >>= 1) {
        mn = fminf(mn, __shfl_down(mn, off));
        mx = fmaxf(mx, __shfl_down(mx, off));
    }
    __shared__ float smn[4], smx[4];
    const int lane = threadIdx.x & 63, wv = threadIdx.x >> 6;
    if (lane == 0) { smn[wv] = mn; smx[wv] = mx; }
    __syncthreads();
    mn = fminf(fminf(smn[0], smn[1]), fminf(smn[2], smn[3]));
    mx = fmaxf(fmaxf(smx[0], smx[1]), fmaxf(smx[2], smx[3]));
}

// slot version: no init kernel, no atomics; block (b,chunk) owns its slot
__global__ __launch_bounds__(256) void minmax_slots(const float* __restrict__ x,
                                                    float* __restrict__ wsf) {
    float mn, mx;
    blk_minmax(x, mn, mx);
    if (threadIdx.x == 0) {
        wsf[blockIdx.y * 16 + blockIdx.x] = mn;
        wsf[1024 + blockIdx.y * 16 + blockIdx.x] = mx;
    }
}

// atomic fallback (ws too small for slots)
__global__ __launch_bounds__(256) void minmax_atomic(const float* __restrict__ x,
                                                     unsigned int* __restrict__ ws) {
    float mn, mx;
    blk_minmax(x, mn, mx);
    if (threadIdx.x == 0) {
        atomicMin(&ws[blockIdx.x], enc_f(mn));
        atomicMax(&ws[16 + blockIdx.x], enc_f(mx));
    }
}

// DPP wave64 inclusive scan (row_shr 1/2/4/8 + row_bcast15/31) — pure VALU
template<int CTRL, int MASK>
__device__ __forceinline__ float dpp_add(float x) {
    int t = __builtin_amdgcn_update_dpp(0, (int)__float_as_uint(x),
                                        CTRL, MASK, 0xf, false);
    return x + __uint_as_float((unsigned)t);
}
template<int CTRL, int MASK>
__device__ __forceinline__ void dpp_step4(float4& v) {
    v.x = dpp_add<CTRL, MASK>(v.x);
    v.y = dpp_add<CTRL, MASK>(v.y);
    v.z = dpp_add<CTRL, MASK>(v.z);
    v.w = dpp_add<CTRL, MASK>(v.w);
}
__device__ __forceinline__ void hscan(float4& v) {
    dpp_step4<0x111, 0xf>(v);   // row_shr:1
    dpp_step4<0x112, 0xf>(v);   // row_shr:2
    dpp_step4<0x114, 0xf>(v);   // row_shr:4
    dpp_step4<0x118, 0xf>(v);   // row_shr:8
    dpp_step4<0x142, 0xa>(v);   // row_bcast15 -> rows 1,3
    dpp_step4<0x143, 0xc>(v);   // row_bcast31 -> rows 2,3
}

#define CL(a) (fmaxf((a), 0.0f) + 1e-7f)

#define BOXD(S, o, sc, bx) {                                             \
        float4 q00 = S[hl + (o)][wl + (o)];                              \
        float4 q01 = S[hl + (o)][wl + (o) + (sc)];                       \
        float4 q10 = S[hl + (o) + (sc)][wl + (o)];                       \
        float4 q11 = S[hl + (o) + (sc)][wl + (o) + (sc)];                \
        bx.x = q11.x - q01.x - q10.x + q00.x;                            \
        bx.y = q11.y - q01.y - q10.y + q00.y;                            \
        bx.z = q11.z - q01.z - q10.z + q00.z;                            \
        bx.w = q11.w - q01.w - q10.w + q00.w; }

// per-quad BN constants, computed ONCE per thread (round-7 hoist):
// out = L*(0.1*t) + (beta - mm*t),  t = gamma*rsqrt(var+eps)
#define BNPREP(qi, wq, oq) {                                             \
        const int ch0 = chbase + (qi) * 4;                               \
        const float4 g4  = *(const float4*)(gamma + ch0);                \
        const float4 be4 = *(const float4*)(beta  + ch0);                \
        const float4 mm4 = *(const float4*)(mmean + ch0);                \
        const float4 mv4 = *(const float4*)(mvar  + ch0);                \
        float t;                                                         \
        t = g4.x * rsqrtf(mv4.x + 1e-3f);                                \
        wq.x = 0.1f * t; oq.x = be4.x - mm4.x * t;                       \
        t = g4.y * rsqrtf(mv4.y + 1e-3f);                                \
        wq.y = 0.1f * t; oq.y = be4.y - mm4.y * t;                       \
        t = g4.z * rsqrtf(mv4.z + 1e-3f);                                \
        wq.z = 0.1f * t; oq.z = be4.z - mm4.z * t;                       \
        t = g4.w * rsqrtf(mv4.w + 1e-3f);                                \
        wq.w = 0.1f * t; oq.w = be4.w - mm4.w * t; }

// combined-log: alpha = 0.1*(log2(m16^3*m8) - log2(m2^3*m4)) (exact fold)
#define LSSCOMP(comp, wq, oq, OUT) {                                     \
        const float a2 = CL(b2.comp),  a4 = CL(b4.comp);                 \
        const float a8 = CL(b8.comp),  a16 = CL(b16.comp);               \
        const float Lq = __log2f(a16 * a16 * a16 * a8)                   \
                       - __log2f(a2 * a2 * a2 * a4);                     \
        OUT = fmaf(Lq, wq.comp, oq.comp); }

#define DOQUAD(qi, wq, oq, o4) {                                         \
        const float4 (*S)[SP] = SAT[qi];                                 \
        float4 b2, b4, b8, b16;                                          \
        BOXD(S, 7, 2, b2);                                               \
        BOXD(S, 6, 4, b4);                                               \
        BOXD(S, 4, 8, b8);                                               \
        BOXD(S, 0, 16, b16);                                             \
        LSSCOMP(x, wq, oq, o4.x); LSSCOMP(y, wq, oq, o4.y);              \
        LSSCOMP(z, wq, oq, o4.z); LSSCOMP(w, wq, oq, o4.w); }

// Round-7: padded SAT stride (49), shuffle-based slot reduce, hoisted BN.
template<bool SLOTS>
__global__ __launch_bounds__(512, 4) void lss_kernel(
    const float* __restrict__ x,
    const float* __restrict__ gamma, const float* __restrict__ beta,
    const float* __restrict__ mmean, const float* __restrict__ mvar,
    const unsigned int* __restrict__ ws,
    float* __restrict__ out)
{
    __shared__ float4 SAT[2][SR][SP];   // 75,264 B -> 2 blocks/CU

    const int bi = blockIdx.x;
    const int grp = bi >> 5, wi = bi & 31;
    const int tile = grp * 8 + (wi & 7);
    const int s  = (wi >> 3) & 1;          // channel half
    const int qp = (wi >> 4) & 1;          // quad pair within half
    const int b = tile / 49;
    const int t2 = tile - b * 49;
    const int th0 = (t2 / 7) * TS;
    const int tw0 = (t2 % 7) * TS;
    const int tid = threadIdx.x;
    const int lane = tid & 63, wv = tid >> 6;   // 8 waves
    const int chbase = s * 16 + qp * 8;

    float mn, mx;
    if (SLOTS) {
        // parallel slot reduce: lane l owns slot l, butterfly across the wave
        const float* wsf = (const float*)ws;
        float vmn = wsf[lane * 16 + b];
        float vmx = wsf[1024 + lane * 16 + b];
#pragma unroll
        for (int off = 32; off > 0; off >>= 1) {
            vmn = fminf(vmn, __shfl_xor(vmn, off));
            vmx = fmaxf(vmx, __shfl_xor(vmx, off));
        }
        mn = vmn; mx = vmx;
    } else {
        mn = dec_f(ws[b]);
        mx = dec_f(ws[16 + b]);
    }
    const float inv = 1.0f / (mx - mn + 1e-7f);
    const float nmi = -mn * inv;

    const float* xb = x + (size_t)b * (H_ * W_ * C_);
    float* ob = out + (size_t)b * (H_ * W_ * C_);

    // ---- P0: load 32B once, scale, DPP h-scan 2 quads, write excl H-prefix ----
#pragma unroll
    for (int p = 0; p < 6; ++p) {
        const int rr = wv + 8 * p;
        if (rr < RG) {
            const int gh = th0 - 7 + rr;
            const int gw = tw0 - 7 + lane;
            float4 q0 = make_float4(0.f, 0.f, 0.f, 0.f);
            float4 q1 = q0;
            if (lane < RG && gh >= 0 && gh < H_ && gw >= 0 && gw < W_) {
                const float4* p4 = (const float4*)(xb +
                    ((size_t)(gh * W_ + gw)) * C_ + chbase);
                q0 = p4[0]; q1 = p4[1];
                q0.x = fmaf(q0.x, inv, nmi); q0.y = fmaf(q0.y, inv, nmi);
                q0.z = fmaf(q0.z, inv, nmi); q0.w = fmaf(q0.w, inv, nmi);
                q1.x = fmaf(q1.x, inv, nmi); q1.y = fmaf(q1.y, inv, nmi);
                q1.z = fmaf(q1.z, inv, nmi); q1.w = fmaf(q1.w, inv, nmi);
            }
            hscan(q0); hscan(q1);
            if (lane < RG) {
                SAT[0][rr][lane + 1] = q0;
                SAT[1][rr][lane + 1] = q1;
            } else if (lane == 63) {
                const float4 z = make_float4(0.f, 0.f, 0.f, 0.f);
                SAT[0][rr][0] = z; SAT[1][rr][0] = z;
            }
        }
    }
    __syncthreads();

    // ---- P1: in-place exclusive vertical scan; 384 scalar columns
    //          (192/plane, cols 0..191 of the 196-word padded row) ----
    {
        int q = -1, c = 0;
        if (tid < 192)      { q = 0; c = tid; }
        else if (tid < 384) { q = 1; c = tid - 192; }
        if (q >= 0) {
            float* col = (float*)&SAT[q][0][0] + c;
            float accv = 0.f;
#pragma unroll
            for (int r = 0; r < SR; ++r) {
                const float t = (r < RG) ? col[r * (SP * 4)] : 0.f;
                col[r * (SP * 4)] = accv;
                accv += t;
            }
        }
    }
    __syncthreads();

    // ---- P2: 2 pixels/thread; 2 planes x 4 scales from SAT corners,
    //          combined-log + hoisted BN, one 32B store per pixel ----
    {
        const int wl = tid & 31;
        const int hl0 = tid >> 5;             // 0..15
        float4 wq0, oq0, wq1, oq1;
        BNPREP(0, wq0, oq0);
        BNPREP(1, wq1, oq1);
#pragma unroll
        for (int pp = 0; pp < 2; ++pp) {
            const int hl = hl0 + pp * 16;
            float4 o0, o1;
            DOQUAD(0, wq0, oq0, o0);
            DOQUAD(1, wq1, oq1, o1);
            float* dst = ob + ((size_t)((th0 + hl) * W_ + (tw0 + wl))) * C_ + chbase;
            *(float4*)(dst + 0) = o0;
            *(float4*)(dst + 4) = o1;
        }
    }
}

extern "C" void kernel_launch(void* const* d_in, const int* in_sizes, int n_in,
                              void* d_out, int out_size, void* d_ws, size_t ws_size,
                              hipStream_t stream) {
    const float* x     = (const float*)d_in[0];
    const float* gamma = (const float*)d_in[1];
    const float* beta  = (const float*)d_in[2];
    const float* mmean = (const float*)d_in[3];
    const float* mvar  = (const float*)d_in[4];
    float* out = (float*)d_out;
    unsigned int* ws = (unsigned int*)d_ws;

    if (ws_size >= 8192) {
        hipLaunchKernelGGL(minmax_slots, dim3(16, 64), dim3(256), 0, stream,
                           x, (float*)ws);
        hipLaunchKernelGGL((lss_kernel<true>), dim3(98 * 32), dim3(512), 0, stream,
                           x, gamma, beta, mmean, mvar, ws, out);
    } else {
        hipLaunchKernelGGL(init_ws, dim3(1), dim3(64), 0, stream, ws);
        hipLaunchKernelGGL(minmax_atomic, dim3(16, 64), dim3(256), 0, stream, x, ws);
        hipLaunchKernelGGL((lss_kernel<false>), dim3(98 * 32), dim3(512), 0, stream,
                           x, gamma, beta, mmean, mvar, ws, out);
    }
}